// Round 4
// baseline (5241.420 us; speedup 1.0000x reference)
//
#include <hip/hip_runtime.h>
#include <cstdint>
#include <cstddef>

// Problem dims (fixed by reference)
#define B_   128
#define T_   32
#define IN_  2048
#define H_   2048
#define OUT_ 512

// address-space helper types for global_load_lds
typedef __attribute__((address_space(1))) const void* gas_cp;
typedef __attribute__((address_space(3))) void* las_p;

// ---------- kernel 1: transpose spikes ----------
__global__ __launch_bounds__(256) void k_transpose(const float* __restrict__ in,
                                                   float* __restrict__ Xt) {
    int idx = blockIdx.x * 256 + threadIdx.x;   // b*IN + i
    int b = idx >> 11;
    int i = idx & (IN_ - 1);
    const float4* p = (const float4*)(in + (size_t)idx * T_);
#pragma unroll
    for (int q = 0; q < 8; ++q) {
        float4 v = p[q];
        int t = q * 4;
        Xt[((size_t)((t + 0) * B_ + b) << 11) + i] = v.x;
        Xt[((size_t)((t + 1) * B_ + b) << 11) + i] = v.y;
        Xt[((size_t)((t + 2) * B_ + b) << 11) + i] = v.z;
        Xt[((size_t)((t + 3) * B_ + b) << 11) + i] = v.w;
    }
}

// ---------- kernel 2a: fp32 GEMM 128x128, 8x8/thread, K=2048 fixed -----------
// Exact-chain semantics preserved:
//   C = ((chain(0..511) + chain(512..1023)) + chain(1024..1535)) + chain(1536..2047)
// ascending-k fp32 FMA chain per C element inside each KC=512 block, plain adds
// joining blocks ascending. Per-element order this round is IDENTICAL to round 3
// (gk ascending, q ascending, folds at k%512==0) — only cross-element scheduling
// and the LDS slot permutation changed.
// ROUND-4: (1) XOR fragment swizzle: LDS slot of (row r, granule s) = s ^ x(r),
//     x(r) = (r + (r>>4)) & 7. Read addr = base_r ^ (gk<<4): ONE v_xor with a
//     literal per read (kt-loop double-unrolled so buffer index is a literal).
//     Conflict profile unchanged: av reads 4 distinct slots (16-lane bcast),
//     wv reads 8 slots x 2 rows = 2-way (free, m136).
// (2) Cross-gk W-fragment double-buffer (wvA/wvB): reads for gk+1 issue before
//     gk's FMA block -> wv latency fully hidden; only the 4 cheap av reads
//     remain on the critical path. Register budget ~240 (waves_per_eu(1,2)
//     grants 256; WRITE_SIZE is the spill tripwire).
__global__ __launch_bounds__(256)
__attribute__((amdgpu_waves_per_eu(1, 2)))
void k_gemm_128(const float* __restrict__ A, const float* __restrict__ W,
                float* __restrict__ C, int M, int N, int K) {
    constexpr int BM = 128, BN = 128, BK = 32;
    constexpr int BUFF = (BM + BN) * BK;        // 8192 floats = 32 KB
    __shared__ alignas(16) float lds[2][BUFF];  // 64 KB double-buffered
    float* lds_f = &lds[0][0];

    const int tid = threadIdx.x;
    const int tx  = tid & 15;        // n direction
    const int ty  = tid >> 4;        // m direction
    const int m0  = blockIdx.y * BM;
    const int n0  = blockIdx.x * BN;
    const int w   = tid >> 6;        // wave id 0..3

    // ---- staging: LDS slot c of row r holds source granule c ^ x(r) ----
    const float* srcA[4];
    int dstA[4], dstW[4];
#pragma unroll
    for (int q = 0; q < 4; ++q) {
        int L = q * 256 + tid;                        // linear granule index
        int r = L >> 3;                               // row 0..127
        int s = (L & 7) ^ ((r + (r >> 4)) & 7);       // source granule
        srcA[q] = A + (size_t)(m0 + r) * K + s * 4;
        dstA[q] = q * 1024 + w * 256;                 // float offset (wave-uniform)
        dstW[q] = BM * BK + q * 1024 + w * 256;
    }
    // W source = A source + uniform delta (same r, same s); saves 8 VGPRs
    const ptrdiff_t wdel = (W - A) + (ptrdiff_t)(n0 - m0) * K;

    // ---- fragment read byte-offsets (granule gk at off ^ (gk<<4)) ----
    int offA[8], offW[8];
#pragma unroll
    for (int i = 0; i < 8; ++i) {
        int r = ty + 16 * i;
        offA[i] = r * 128 + (((r + (r >> 4)) & 7) << 4);
    }
#pragma unroll
    for (int j = 0; j < 8; ++j) {
        int r = tx + 16 * j;
        offW[j] = BM * BK * 4 + r * 128 + (((r + (r >> 4)) & 7) << 4);
    }

    float acc[8][8];                 // in-block FMA chain
    float tot[8][8];                 // cross-block joins (plain adds)
#pragma unroll
    for (int i = 0; i < 8; ++i)
#pragma unroll
        for (int j = 0; j < 8; ++j) { acc[i][j] = 0.0f; tot[i][j] = 0.0f; }

#define RD4(BB, OFF) (*(const float4*)((const char*)lds_f + (BB) * 32768 + (OFF)))

#define PREFETCH(NB)                                                        \
    {                                                                       \
        _Pragma("unroll")                                                   \
        for (int q = 0; q < 4; ++q) {                                       \
            __builtin_amdgcn_global_load_lds((gas_cp)srcA[q],               \
                (las_p)&lds_f[(NB) * BUFF + dstA[q]], 16, 0, 0);            \
            __builtin_amdgcn_global_load_lds((gas_cp)(srcA[q] + wdel),      \
                (las_p)&lds_f[(NB) * BUFF + dstW[q]], 16, 0, 0);            \
            srcA[q] += BK;                                                  \
        }                                                                   \
    }

// One gk step: av chunk reads + next-gk wv reads + FMA blocks.
// Per acc element: q ascends within gk, gk ascends across steps -> exact chain.
#define GKSTEP(BB, GKC, WC, WN, LOADN)                                      \
    {                                                                       \
        float4 av[4];                                                       \
        _Pragma("unroll")                                                   \
        for (int i = 0; i < 4; ++i) av[i] = RD4(BB, offA[i] ^ (GKC));       \
        if (LOADN) {                                                        \
            _Pragma("unroll")                                               \
            for (int j = 0; j < 8; ++j) WN[j] = RD4(BB, offW[j] ^ ((GKC) + 16)); \
        }                                                                   \
        _Pragma("unroll")                                                   \
        for (int q = 0; q < 4; ++q)                                         \
            _Pragma("unroll")                                               \
            for (int i = 0; i < 4; ++i)                                     \
                _Pragma("unroll")                                           \
                for (int j = 0; j < 8; ++j)                                 \
                    acc[i][j] = __builtin_fmaf(((const float*)&av[i])[q],   \
                                               ((const float*)&WC[j])[q],   \
                                               acc[i][j]);                  \
        _Pragma("unroll")                                                   \
        for (int i = 0; i < 4; ++i) av[i] = RD4(BB, offA[4 + i] ^ (GKC));   \
        _Pragma("unroll")                                                   \
        for (int q = 0; q < 4; ++q)                                         \
            _Pragma("unroll")                                               \
            for (int i = 0; i < 4; ++i)                                     \
                _Pragma("unroll")                                           \
                for (int j = 0; j < 8; ++j)                                 \
                    acc[4 + i][j] = __builtin_fmaf(((const float*)&av[i])[q], \
                                                   ((const float*)&WC[j])[q], \
                                                   acc[4 + i][j]);          \
    }

#define KTILE(BB, DO_PF, NB)                                                \
    {                                                                       \
        __syncthreads();                                                    \
        if (DO_PF) PREFETCH(NB);                                            \
        float4 wvA[8], wvB[8];                                              \
        _Pragma("unroll")                                                   \
        for (int j = 0; j < 8; ++j) wvA[j] = RD4(BB, offW[j]);              \
        GKSTEP(BB, 0,   wvA, wvB, 1)                                        \
        GKSTEP(BB, 16,  wvB, wvA, 1)                                        \
        GKSTEP(BB, 32,  wvA, wvB, 1)                                        \
        GKSTEP(BB, 48,  wvB, wvA, 1)                                        \
        GKSTEP(BB, 64,  wvA, wvB, 1)                                        \
        GKSTEP(BB, 80,  wvB, wvA, 1)                                        \
        GKSTEP(BB, 96,  wvA, wvB, 1)                                        \
        GKSTEP(BB, 112, wvB, wvA, 0)                                        \
    }

    // prologue: stage tile 0 into buffer 0
    PREFETCH(0);

    // K = 2048 for both big layers: 64 K-tiles, double-unrolled so the
    // buffer index is a compile-time literal.
    for (int kt = 0; kt < 64; kt += 2) {
        // tile kt (even) in buffer 0; prefetch tile kt+1 -> buffer 1 (always exists)
        KTILE(0, 1, 1)
        // fold never fires after even tiles ((kt+1) odd)
        // tile kt+1 (odd) in buffer 1; prefetch tile kt+2 -> buffer 0
        KTILE(1, (kt < 62), 0)
        if (((kt + 2) & 15) == 0) {      // after tiles 15,31,47,63: KC=512 join
#pragma unroll
            for (int i = 0; i < 8; ++i)
#pragma unroll
                for (int j = 0; j < 8; ++j) {
                    tot[i][j] = tot[i][j] + acc[i][j];
                    acc[i][j] = 0.0f;
                }
        }
    }

#pragma unroll
    for (int i = 0; i < 8; ++i)
#pragma unroll
        for (int j = 0; j < 8; ++j)
            C[(size_t)(m0 + ty + 16 * i) * N + (n0 + tx + 16 * j)] = tot[i][j];

#undef KTILE
#undef GKSTEP
#undef PREFETCH
#undef RD4
}

// ---------- kernel 2b: fp32 GEMM 64x128 tile, 4x8/thread (output layer) ------
// Same exact-chain semantics; kept unchanged (verified round 1/3) for N=512.
__global__ __launch_bounds__(256)
void k_gemm_seq(const float* __restrict__ A, const float* __restrict__ W,
                float* __restrict__ C, int M, int N, int K) {
    constexpr int BM = 64, BN = 128, BK = 32;
    constexpr int NT = 8;                       // n per thread (BN/16)
    constexpr int BUFF = (BM + BN) * BK;        // 6144 floats = 24 KB
    __shared__ alignas(16) float lds[2][BUFF];  // 48 KB double-buffered

    const int tid = threadIdx.x;
    const int tx  = tid & 15;        // n direction
    const int ty  = tid >> 4;        // m direction
    const int m0  = blockIdx.y * BM;
    const int n0  = blockIdx.x * BN;
    const int w   = tid >> 6;        // wave id 0..3

    const float* srcA[2];
    int dstA[2];
#pragma unroll
    for (int q = 0; q < 2; ++q) {
        int L = q * 256 + tid;
        int r = L >> 3;
        int s = ((L & 7) - ((r + (r >> 4)) & 7)) & 7;
        srcA[q] = A + (size_t)(m0 + r) * K + s * 4;
        dstA[q] = q * 1024 + w * 256;
    }
    const float* srcW[4];
    int dstW[4];
#pragma unroll
    for (int q = 0; q < 4; ++q) {
        int L = q * 256 + tid;
        int r = L >> 3;
        int s = ((L & 7) - ((r + (r >> 4)) & 7)) & 7;
        srcW[q] = W + (size_t)(n0 + r) * K + s * 4;
        dstW[q] = BM * BK + q * 1024 + w * 256;
    }

    float acc[4][NT];
    float tot[4][NT];
#pragma unroll
    for (int i = 0; i < 4; ++i)
#pragma unroll
        for (int j = 0; j < NT; ++j) { acc[i][j] = 0.0f; tot[i][j] = 0.0f; }

    const int nkt = K / BK;

#pragma unroll
    for (int q = 0; q < 2; ++q) {
        __builtin_amdgcn_global_load_lds((gas_cp)srcA[q], (las_p)&lds[0][dstA[q]], 16, 0, 0);
        srcA[q] += BK;
    }
#pragma unroll
    for (int q = 0; q < 4; ++q) {
        __builtin_amdgcn_global_load_lds((gas_cp)srcW[q], (las_p)&lds[0][dstW[q]], 16, 0, 0);
        srcW[q] += BK;
    }

    int cur = 0;
    for (int kt = 0; kt < nkt; ++kt) {
        __syncthreads();

        if (kt + 1 < nkt) {
            int nb = cur ^ 1;
#pragma unroll
            for (int q = 0; q < 2; ++q) {
                __builtin_amdgcn_global_load_lds((gas_cp)srcA[q], (las_p)&lds[nb][dstA[q]], 16, 0, 0);
                srcA[q] += BK;
            }
#pragma unroll
            for (int q = 0; q < 4; ++q) {
                __builtin_amdgcn_global_load_lds((gas_cp)srcW[q], (las_p)&lds[nb][dstW[q]], 16, 0, 0);
                srcW[q] += BK;
            }
        }

        const float* At = &lds[cur][0];
        const float* Wt = &lds[cur][BM * BK];

#pragma unroll
        for (int gk = 0; gk < 8; ++gk) {
            float4 av[4], wv[NT];
#pragma unroll
            for (int i = 0; i < 4; ++i) {
                int r = ty + 16 * i;
                int rot = (r + (r >> 4)) & 7;
                av[i] = *(const float4*)&At[r * BK + (((gk + rot) & 7) << 2)];
            }
#pragma unroll
            for (int j = 0; j < NT; ++j) {
                int r = tx + 16 * j;
                int rot = (r + (r >> 4)) & 7;
                wv[j] = *(const float4*)&Wt[r * BK + (((gk + rot) & 7) << 2)];
            }
#pragma unroll
            for (int q = 0; q < 4; ++q)
#pragma unroll
                for (int i = 0; i < 4; ++i)
#pragma unroll
                    for (int j = 0; j < NT; ++j)
                        acc[i][j] = __builtin_fmaf(((const float*)&av[i])[q],
                                                   ((const float*)&wv[j])[q],
                                                   acc[i][j]);
        }

        if (((kt + 1) & 15) == 0) {
#pragma unroll
            for (int i = 0; i < 4; ++i)
#pragma unroll
                for (int j = 0; j < NT; ++j) {
                    tot[i][j] = tot[i][j] + acc[i][j];
                    acc[i][j] = 0.0f;
                }
        }
        cur ^= 1;
    }

#pragma unroll
    for (int i = 0; i < 4; ++i)
#pragma unroll
        for (int j = 0; j < NT; ++j)
            C[(size_t)(m0 + ty + 16 * i) * N + (n0 + tx + 16 * j)] = tot[i][j];
}

// ---------- kernel 3: LIF scan over t for hidden layers (fp32, numpy order) --
__global__ __launch_bounds__(256) void k_scan_h(const float* __restrict__ Acc,
                                                const float* __restrict__ v_init,
                                                const float* __restrict__ s_init,
                                                const float* __restrict__ bias,
                                                float* __restrict__ Sout) {
    int idx = blockIdx.x * 256 + threadIdx.x;  // b*H + h
    int h = idx & (H_ - 1);
    float v = v_init[idx];
    float s = s_init[idx];
    float bb = bias[h];
#pragma unroll
    for (int t = 0; t < T_; ++t) {
        float x = Acc[(size_t)t * (B_ * H_) + idx];
        float d = 0.5f * v;          // exact (power of two)
        d = d * (1.0f - s);          // exact (x{0,1})
        v = d + x;
        v = v + bb;
        s = (v > 0.5f) ? 1.0f : 0.0f;
        Sout[(size_t)t * (B_ * H_) + idx] = s;
    }
}

// ---------- kernel 4: LIF scan + spike count for output layer ----------
__global__ __launch_bounds__(256) void k_scan_o(const float* __restrict__ Acc,
                                                const float* __restrict__ v_init,
                                                const float* __restrict__ s_init,
                                                const float* __restrict__ bias,
                                                float* __restrict__ out) {
    int idx = blockIdx.x * 256 + threadIdx.x;  // b*OUT + o
    int o = idx & (OUT_ - 1);
    float v = v_init[idx];
    float s = s_init[idx];
    float bb = bias[o];
    float acc = 0.0f;
#pragma unroll
    for (int t = 0; t < T_; ++t) {
        float x = Acc[(size_t)t * (B_ * OUT_) + idx];
        float d = 0.5f * v;
        d = d * (1.0f - s);
        v = d + x;
        v = v + bb;
        s = (v > 0.5f) ? 1.0f : 0.0f;
        acc += s;                    // integer-valued, exact in fp32
    }
    out[idx] = acc;
}

// ---------- launch ----------

extern "C" void kernel_launch(void* const* d_in, const int* in_sizes, int n_in,
                              void* d_out, int out_size, void* d_ws, size_t ws_size,
                              hipStream_t stream) {
    const float* spike_data = (const float*)d_in[0];
    const float* h0_volt  = (const float*)d_in[1];
    const float* h0_spike = (const float*)d_in[2];
    const float* h1_volt  = (const float*)d_in[3];
    const float* h1_spike = (const float*)d_in[4];
    const float* o_volt   = (const float*)d_in[5];
    const float* o_spike  = (const float*)d_in[6];
    const float* W0 = (const float*)d_in[7];
    const float* b0 = (const float*)d_in[8];
    const float* W1 = (const float*)d_in[9];
    const float* b1 = (const float*)d_in[10];
    const float* Wo = (const float*)d_in[11];
    const float* bo = (const float*)d_in[12];
    float* out = (float*)d_out;

    // workspace layout (96 MB)
    char* ws = (char*)d_ws;
    const size_t MB = (size_t)1 << 20;
    float* Xt = (float*)(ws);             // 32 MB [T*B][IN]; reused as S1
    float* S0 = (float*)(ws + 32 * MB);   // 32 MB [T*B][H]
    float* Ab = (float*)(ws + 64 * MB);   // 32 MB [T*B][H] (or [T*B][OUT])
    float* S1 = Xt;                       // Xt dead after GEMM0

    const int M = T_ * B_;   // 4096

    k_transpose<<<(B_ * IN_) / 256, 256, 0, stream>>>(spike_data, Xt);

    // layer 0: A0 = Xt @ W0^T   [4096,2048] x [2048,2048]
    k_gemm_128<<<dim3(H_ / 128, M / 128), 256, 0, stream>>>(Xt, W0, Ab, M, H_, IN_);
    k_scan_h<<<(B_ * H_) / 256, 256, 0, stream>>>(Ab, h0_volt, h0_spike, b0, S0);

    // layer 1: A1 = S0 @ W1^T
    k_gemm_128<<<dim3(H_ / 128, M / 128), 256, 0, stream>>>(S0, W1, Ab, M, H_, H_);
    k_scan_h<<<(B_ * H_) / 256, 256, 0, stream>>>(Ab, h1_volt, h1_spike, b1, S1);

    // output: Ao = S1 @ Wo^T   [4096,2048] x [2048,512]
    k_gemm_seq<<<dim3(OUT_ / 128, M / 64), 256, 0, stream>>>(S1, Wo, Ab, M, OUT_, H_);
    k_scan_o<<<(B_ * OUT_) / 256, 256, 0, stream>>>(Ab, o_volt, o_spike, bo, out);

    (void)in_sizes; (void)n_in; (void)out_size; (void)ws_size;
}

// Round 5
// 2196.330 us; speedup vs baseline: 2.3864x; 2.3864x over previous
//
#include <hip/hip_runtime.h>
#include <cstdint>

// Problem dims (fixed by reference)
#define B_   128
#define T_   32
#define IN_  2048
#define H_   2048
#define OUT_ 512

// address-space helper types for global_load_lds
typedef __attribute__((address_space(1))) const void* gas_cp;
typedef __attribute__((address_space(3))) void* las_p;

// ---------- kernel 1: transpose spikes ----------
// in:  spike_data [B][IN][T] f32 (values exactly 0.0/1.0)
// out: Xt [T*B][IN] f32 (same bit values, relocated)
__global__ __launch_bounds__(256) void k_transpose(const float* __restrict__ in,
                                                   float* __restrict__ Xt) {
    int idx = blockIdx.x * 256 + threadIdx.x;   // b*IN + i
    int b = idx >> 11;
    int i = idx & (IN_ - 1);
    const float4* p = (const float4*)(in + (size_t)idx * T_);
#pragma unroll
    for (int q = 0; q < 8; ++q) {
        float4 v = p[q];
        int t = q * 4;
        Xt[((size_t)((t + 0) * B_ + b) << 11) + i] = v.x;
        Xt[((size_t)((t + 1) * B_ + b) << 11) + i] = v.y;
        Xt[((size_t)((t + 2) * B_ + b) << 11) + i] = v.z;
        Xt[((size_t)((t + 3) * B_ + b) << 11) + i] = v.w;
    }
}

// ---------- kernel 2a: fp32 GEMM 128x128 tile, 512 threads, 4x8/thread ------
// Exact-chain semantics preserved (verified through round 3):
//   C = ((chain(0..511) + chain(512..1023)) + chain(1024..1535)) + chain(1536..2047)
// ascending-k fp32 FMA chain per C element in each KC=512 block (kt asc, gk asc,
// q asc), plain fp32 adds joining blocks ascending. Thread->element map changes
// only cross-element scheduling, never any element's chain.
// ROUND-5 rationale: round-1 (64x128, 4x8/thr, VGPR 124) = 567us @ 3 waves/SIMD;
// round-3 (128x128, 8x8/thr, VGPR 192) = 592us @ 2 waves/SIMD; round-4 wv-dbuf
// spilled (VGPR 256, 1.9GB scratch). Per-wave duty ~32% is stall-dominated
// (barrier skew + LDS latency), so waves/SIMD is the lever:
//   512 threads x 4x8/thread (round-1's exact per-thread register profile,
//   ~120 regs) on a 128x128 tile -> 2 blocks/CU x 8 waves = 4 waves/SIMD,
//   grid 512 = exactly 2 blocks/CU, zero tail.
// amdgpu_waves_per_eu(4,4) pins the allocator budget at 512/4 = 128 VGPRs
// (round-2 lesson: the allocator targets this attribute, not launch_bounds).
// Staging via global_load_lds(16B); granule rotation pre-applied on the GLOBAL
// source address (rule #21): slot c of row r holds source granule (c-rot(r))&7,
// rot(r) = (r + (r>>4)) & 7; fragment read at slot (gk+rot(r))&7 returns
// granule gk. av reads: 16-lane broadcast, conflict-free; wv reads: 2-way (free).
__global__ __launch_bounds__(512)
__attribute__((amdgpu_waves_per_eu(4, 4)))
void k_gemm_128(const float* __restrict__ A, const float* __restrict__ W,
                float* __restrict__ C, int M, int N, int K) {
    constexpr int BM = 128, BN = 128, BK = 32;
    constexpr int BUFF = (BM + BN) * BK;        // 8192 floats = 32 KB
    __shared__ alignas(16) float lds[2][BUFF];  // 64 KB double-buffered

    const int tid = threadIdx.x;     // 0..511
    const int tx  = tid & 15;        // n direction (16 cols of threads)
    const int ty  = tid >> 4;        // m direction (32 rows of threads)
    const int m0  = blockIdx.y * BM;
    const int n0  = blockIdx.x * BN;
    const int w   = tid >> 6;        // wave id 0..7

    // Pre-swizzled per-lane global sources + wave-uniform LDS dest offsets.
    // Each tile: 128 rows x 8 granules = 1024 granules -> 2 glds per thread
    // per operand.
    const float* srcA[2];
    const float* srcW[2];
    int dstA[2], dstW[2];
#pragma unroll
    for (int q = 0; q < 2; ++q) {
        int L = q * 512 + tid;                        // linear granule index
        int r = L >> 3;                               // row 0..127
        int s = ((L & 7) - ((r + (r >> 4)) & 7)) & 7; // source granule (inv rot)
        srcA[q] = A + (size_t)(m0 + r) * K + s * 4;
        srcW[q] = W + (size_t)(n0 + r) * K + s * 4;
        dstA[q] = q * 2048 + w * 256;                 // float offset (wave-uniform)
        dstW[q] = BM * BK + q * 2048 + w * 256;
    }

    float acc[4][8];                 // in-block FMA chain
    float tot[4][8];                 // cross-block joins (plain adds)
#pragma unroll
    for (int i = 0; i < 4; ++i)
#pragma unroll
        for (int j = 0; j < 8; ++j) { acc[i][j] = 0.0f; tot[i][j] = 0.0f; }

    const int nkt = K / BK;

    // prologue: stage tile 0 into buffer 0
#pragma unroll
    for (int q = 0; q < 2; ++q) {
        __builtin_amdgcn_global_load_lds((gas_cp)srcA[q], (las_p)&lds[0][dstA[q]], 16, 0, 0);
        __builtin_amdgcn_global_load_lds((gas_cp)srcW[q], (las_p)&lds[0][dstW[q]], 16, 0, 0);
        srcA[q] += BK;
        srcW[q] += BK;
    }

    int cur = 0;
    for (int kt = 0; kt < nkt; ++kt) {
        __syncthreads();             // drains vmcnt: buf[cur] staged & visible

        if (kt + 1 < nkt) {          // async prefetch of next tile into buf^1
            int nb = cur ^ 1;
#pragma unroll
            for (int q = 0; q < 2; ++q) {
                __builtin_amdgcn_global_load_lds((gas_cp)srcA[q], (las_p)&lds[nb][dstA[q]], 16, 0, 0);
                __builtin_amdgcn_global_load_lds((gas_cp)srcW[q], (las_p)&lds[nb][dstW[q]], 16, 0, 0);
                srcA[q] += BK;
                srcW[q] += BK;
            }
        }

        const float* At = &lds[cur][0];
        const float* Wt = &lds[cur][BM * BK];

#pragma unroll
        for (int gk = 0; gk < 8; ++gk) {        // granule = 4 consecutive k
            float4 av[4], wv[8];
#pragma unroll
            for (int i = 0; i < 4; ++i) {
                int r = ty + 32 * i;
                int rot = (r + (r >> 4)) & 7;
                av[i] = *(const float4*)&At[r * BK + (((gk + rot) & 7) << 2)];
            }
#pragma unroll
            for (int j = 0; j < 8; ++j) {
                int r = tx + 16 * j;
                int rot = (r + (r >> 4)) & 7;
                wv[j] = *(const float4*)&Wt[r * BK + (((gk + rot) & 7) << 2)];
            }
            // strictly ascending k within the granule; 32 independent chains
#pragma unroll
            for (int q = 0; q < 4; ++q)
#pragma unroll
                for (int i = 0; i < 4; ++i)
#pragma unroll
                    for (int j = 0; j < 8; ++j)
                        acc[i][j] = __builtin_fmaf(((const float*)&av[i])[q],
                                                   ((const float*)&wv[j])[q],
                                                   acc[i][j]);
        }

        // KC=512 block boundary: fold in-block chain into the C-join
        // accumulator with a plain fp32 add (BLIS C += A_blk*B_blk).
        if (((kt + 1) & 15) == 0) {
#pragma unroll
            for (int i = 0; i < 4; ++i)
#pragma unroll
                for (int j = 0; j < 8; ++j) {
                    tot[i][j] = tot[i][j] + acc[i][j];
                    acc[i][j] = 0.0f;
                }
        }
        cur ^= 1;
    }

#pragma unroll
    for (int i = 0; i < 4; ++i)
#pragma unroll
        for (int j = 0; j < 8; ++j)
            C[(size_t)(m0 + ty + 32 * i) * N + (n0 + tx + 16 * j)] = tot[i][j];
}

// ---------- kernel 2b: fp32 GEMM 64x128 tile, 4x8/thread (output layer) ------
// Round-1 kernel verbatim (proven). N=512: grid (4,64) = 256 blocks = 1/CU.
__global__ __launch_bounds__(256)
void k_gemm_seq(const float* __restrict__ A, const float* __restrict__ W,
                float* __restrict__ C, int M, int N, int K) {
    constexpr int BM = 64, BN = 128, BK = 32;
    constexpr int NT = 8;                       // n per thread (BN/16)
    constexpr int BUFF = (BM + BN) * BK;        // 6144 floats = 24 KB
    __shared__ alignas(16) float lds[2][BUFF];  // 48 KB double-buffered

    const int tid = threadIdx.x;
    const int tx  = tid & 15;        // n direction
    const int ty  = tid >> 4;        // m direction
    const int m0  = blockIdx.y * BM;
    const int n0  = blockIdx.x * BN;
    const int w   = tid >> 6;        // wave id 0..3

    const float* srcA[2];
    int dstA[2];
#pragma unroll
    for (int q = 0; q < 2; ++q) {
        int L = q * 256 + tid;
        int r = L >> 3;
        int s = ((L & 7) - ((r + (r >> 4)) & 7)) & 7;
        srcA[q] = A + (size_t)(m0 + r) * K + s * 4;
        dstA[q] = q * 1024 + w * 256;
    }
    const float* srcW[4];
    int dstW[4];
#pragma unroll
    for (int q = 0; q < 4; ++q) {
        int L = q * 256 + tid;
        int r = L >> 3;
        int s = ((L & 7) - ((r + (r >> 4)) & 7)) & 7;
        srcW[q] = W + (size_t)(n0 + r) * K + s * 4;
        dstW[q] = BM * BK + q * 1024 + w * 256;
    }

    float acc[4][NT];
    float tot[4][NT];
#pragma unroll
    for (int i = 0; i < 4; ++i)
#pragma unroll
        for (int j = 0; j < NT; ++j) { acc[i][j] = 0.0f; tot[i][j] = 0.0f; }

    const int nkt = K / BK;

#pragma unroll
    for (int q = 0; q < 2; ++q) {
        __builtin_amdgcn_global_load_lds((gas_cp)srcA[q], (las_p)&lds[0][dstA[q]], 16, 0, 0);
        srcA[q] += BK;
    }
#pragma unroll
    for (int q = 0; q < 4; ++q) {
        __builtin_amdgcn_global_load_lds((gas_cp)srcW[q], (las_p)&lds[0][dstW[q]], 16, 0, 0);
        srcW[q] += BK;
    }

    int cur = 0;
    for (int kt = 0; kt < nkt; ++kt) {
        __syncthreads();

        if (kt + 1 < nkt) {
            int nb = cur ^ 1;
#pragma unroll
            for (int q = 0; q < 2; ++q) {
                __builtin_amdgcn_global_load_lds((gas_cp)srcA[q], (las_p)&lds[nb][dstA[q]], 16, 0, 0);
                srcA[q] += BK;
            }
#pragma unroll
            for (int q = 0; q < 4; ++q) {
                __builtin_amdgcn_global_load_lds((gas_cp)srcW[q], (las_p)&lds[nb][dstW[q]], 16, 0, 0);
                srcW[q] += BK;
            }
        }

        const float* At = &lds[cur][0];
        const float* Wt = &lds[cur][BM * BK];

#pragma unroll
        for (int gk = 0; gk < 8; ++gk) {
            float4 av[4], wv[NT];
#pragma unroll
            for (int i = 0; i < 4; ++i) {
                int r = ty + 16 * i;
                int rot = (r + (r >> 4)) & 7;
                av[i] = *(const float4*)&At[r * BK + (((gk + rot) & 7) << 2)];
            }
#pragma unroll
            for (int j = 0; j < NT; ++j) {
                int r = tx + 16 * j;
                int rot = (r + (r >> 4)) & 7;
                wv[j] = *(const float4*)&Wt[r * BK + (((gk + rot) & 7) << 2)];
            }
#pragma unroll
            for (int q = 0; q < 4; ++q)
#pragma unroll
                for (int i = 0; i < 4; ++i)
#pragma unroll
                    for (int j = 0; j < NT; ++j)
                        acc[i][j] = __builtin_fmaf(((const float*)&av[i])[q],
                                                   ((const float*)&wv[j])[q],
                                                   acc[i][j]);
        }

        if (((kt + 1) & 15) == 0) {
#pragma unroll
            for (int i = 0; i < 4; ++i)
#pragma unroll
                for (int j = 0; j < NT; ++j) {
                    tot[i][j] = tot[i][j] + acc[i][j];
                    acc[i][j] = 0.0f;
                }
        }
        cur ^= 1;
    }

#pragma unroll
    for (int i = 0; i < 4; ++i)
#pragma unroll
        for (int j = 0; j < NT; ++j)
            C[(size_t)(m0 + ty + 16 * i) * N + (n0 + tx + 16 * j)] = tot[i][j];
}

// ---------- kernel 3: LIF scan over t for hidden layers (fp32, numpy order) --
// volt = (0.5f*v)*(1-s) + x + b ; spike = volt > 0.5f     (biases are zero)
__global__ __launch_bounds__(256) void k_scan_h(const float* __restrict__ Acc,
                                                const float* __restrict__ v_init,
                                                const float* __restrict__ s_init,
                                                const float* __restrict__ bias,
                                                float* __restrict__ Sout) {
    int idx = blockIdx.x * 256 + threadIdx.x;  // b*H + h
    int h = idx & (H_ - 1);
    float v = v_init[idx];
    float s = s_init[idx];
    float bb = bias[h];
#pragma unroll
    for (int t = 0; t < T_; ++t) {
        float x = Acc[(size_t)t * (B_ * H_) + idx];
        float d = 0.5f * v;          // exact (power of two)
        d = d * (1.0f - s);          // exact (x{0,1})
        v = d + x;
        v = v + bb;
        s = (v > 0.5f) ? 1.0f : 0.0f;
        Sout[(size_t)t * (B_ * H_) + idx] = s;
    }
}

// ---------- kernel 4: LIF scan + spike count for output layer ----------
__global__ __launch_bounds__(256) void k_scan_o(const float* __restrict__ Acc,
                                                const float* __restrict__ v_init,
                                                const float* __restrict__ s_init,
                                                const float* __restrict__ bias,
                                                float* __restrict__ out) {
    int idx = blockIdx.x * 256 + threadIdx.x;  // b*OUT + o
    int o = idx & (OUT_ - 1);
    float v = v_init[idx];
    float s = s_init[idx];
    float bb = bias[o];
    float acc = 0.0f;
#pragma unroll
    for (int t = 0; t < T_; ++t) {
        float x = Acc[(size_t)t * (B_ * OUT_) + idx];
        float d = 0.5f * v;
        d = d * (1.0f - s);
        v = d + x;
        v = v + bb;
        s = (v > 0.5f) ? 1.0f : 0.0f;
        acc += s;                    // integer-valued, exact in fp32
    }
    out[idx] = acc;
}

// ---------- launch ----------

extern "C" void kernel_launch(void* const* d_in, const int* in_sizes, int n_in,
                              void* d_out, int out_size, void* d_ws, size_t ws_size,
                              hipStream_t stream) {
    const float* spike_data = (const float*)d_in[0];
    const float* h0_volt  = (const float*)d_in[1];
    const float* h0_spike = (const float*)d_in[2];
    const float* h1_volt  = (const float*)d_in[3];
    const float* h1_spike = (const float*)d_in[4];
    const float* o_volt   = (const float*)d_in[5];
    const float* o_spike  = (const float*)d_in[6];
    const float* W0 = (const float*)d_in[7];
    const float* b0 = (const float*)d_in[8];
    const float* W1 = (const float*)d_in[9];
    const float* b1 = (const float*)d_in[10];
    const float* Wo = (const float*)d_in[11];
    const float* bo = (const float*)d_in[12];
    float* out = (float*)d_out;

    // workspace layout (96 MB)
    char* ws = (char*)d_ws;
    const size_t MB = (size_t)1 << 20;
    float* Xt = (float*)(ws);             // 32 MB [T*B][IN]; reused as S1
    float* S0 = (float*)(ws + 32 * MB);   // 32 MB [T*B][H]
    float* Ab = (float*)(ws + 64 * MB);   // 32 MB [T*B][H] (or [T*B][OUT])
    float* S1 = Xt;                       // Xt dead after GEMM0

    const int M = T_ * B_;   // 4096

    k_transpose<<<(B_ * IN_) / 256, 256, 0, stream>>>(spike_data, Xt);

    // layer 0: A0 = Xt @ W0^T   [4096,2048] x [2048,2048]
    k_gemm_128<<<dim3(H_ / 128, M / 128), 512, 0, stream>>>(Xt, W0, Ab, M, H_, IN_);
    k_scan_h<<<(B_ * H_) / 256, 256, 0, stream>>>(Ab, h0_volt, h0_spike, b0, S0);

    // layer 1: A1 = S0 @ W1^T
    k_gemm_128<<<dim3(H_ / 128, M / 128), 512, 0, stream>>>(S0, W1, Ab, M, H_, H_);
    k_scan_h<<<(B_ * H_) / 256, 256, 0, stream>>>(Ab, h1_volt, h1_spike, b1, S1);

    // output: Ao = S1 @ Wo^T   [4096,2048] x [2048,512]
    k_gemm_seq<<<dim3(OUT_ / 128, M / 64), 256, 0, stream>>>(S1, Wo, Ab, M, OUT_, H_);
    k_scan_o<<<(B_ * OUT_) / 256, 256, 0, stream>>>(Ab, o_volt, o_spike, bo, out);

    (void)in_sizes; (void)n_in; (void)out_size; (void)ws_size;
}

// Round 6
// 1373.531 us; speedup vs baseline: 3.8160x; 1.5990x over previous
//
#include <hip/hip_runtime.h>
#include <cstdint>
#include <cstddef>

// Problem dims (fixed by reference)
#define B_   128
#define T_   32
#define IN_  2048
#define H_   2048
#define OUT_ 512

// address-space helper types for global_load_lds
typedef __attribute__((address_space(1))) const void* gas_cp;
typedef __attribute__((address_space(3))) void* las_p;

// ---------- kernel 1: transpose spikes ----------
__global__ __launch_bounds__(256) void k_transpose(const float* __restrict__ in,
                                                   float* __restrict__ Xt) {
    int idx = blockIdx.x * 256 + threadIdx.x;   // b*IN + i
    int b = idx >> 11;
    int i = idx & (IN_ - 1);
    const float4* p = (const float4*)(in + (size_t)idx * T_);
#pragma unroll
    for (int q = 0; q < 8; ++q) {
        float4 v = p[q];
        int t = q * 4;
        Xt[((size_t)((t + 0) * B_ + b) << 11) + i] = v.x;
        Xt[((size_t)((t + 1) * B_ + b) << 11) + i] = v.y;
        Xt[((size_t)((t + 2) * B_ + b) << 11) + i] = v.z;
        Xt[((size_t)((t + 3) * B_ + b) << 11) + i] = v.w;
    }
}

// ---------- kernel 2a: fp32 GEMM 128x128, BK=16, 8x8/thread, C-RMW ----------
// Exact-chain semantics preserved:
//   C = ((chain(0..511) + chain(512..1023)) + chain(1024..1535)) + chain(1536..2047)
// per C element: ascending-k fp32 FMA chain within each KC=512 block (kt asc,
// gk asc, q asc), KC blocks joined by plain fp32 adds ascending. The join is
// now done in GLOBAL memory by the owning thread: C=c1; C+=c2; C+=c3; C+=c4
// (volatile, same thread, ascending order -> identical rounding to tot-in-reg).
// This frees tot[64] regs so the 8x8 tile (1.0 LDS-B/FMA) fits 3 waves/SIMD.
// BK=16 -> 32 KB LDS dbuf -> 3 blocks/CU (reg-capped), grid 512 blocks.
// Round-1 was LDS-throughput-bound (1.5 B/FMA ~ 87% LDS busy); this is the
// 1.0 B/FMA + 3 waves/SIMD point.
// Pair-row XOR swizzle (full 128B line = rows {2u,2u+1} x 8 granule slots):
// granule (row r, s) stored at group u=r>>1, slot ((s<<1)|(r&1)) ^ (u&7),
// pre-applied on the glds GLOBAL source (rule #21). Fragment read address =
// base ^ (gk<<5): ONE v_xor with a literal per ds_read_b128.
//   av reads: 16-lane broadcast (4 addrs/wave) -> conflict-free.
//   wv reads: 16 distinct lines, each slot value hit 2x -> 2-way (free, m136).
// Occupancy control: amdgpu_waves_per_eu(2,3) — max>=target, never exact-pin
// (round-5 lesson: (4,4) forced a 64-reg spill disaster; (1,2) behaved).
__global__ __launch_bounds__(256)
__attribute__((amdgpu_waves_per_eu(2, 3)))
void k_gemm_128(const float* __restrict__ A, const float* __restrict__ W,
                float* __restrict__ C, int M, int N, int K) {
    constexpr int BK = 16;
    constexpr int BUFF = 4096;                  // floats per buffer (16 KB)
    __shared__ alignas(16) float lds[2][BUFF];  // 32 KB double-buffered

    const int tid = threadIdx.x;
    const int tx  = tid & 15;        // n direction
    const int ty  = tid >> 4;        // m direction
    const int m0  = blockIdx.y * 128;
    const int n0  = blockIdx.x * 128;
    const int w   = tid >> 6;        // wave id 0..3

    // ---- staging: per tile 512 granules per operand -> 2 glds/thread each.
    // LDS linear slot L=(u,c) receives source (row 2u+h, granule s) where
    // v = c ^ (u&7), h = v&1, s = v>>1.
    const float* srcA[2];
    const float* srcW[2];
    int dstA[2], dstW[2];
#pragma unroll
    for (int q = 0; q < 2; ++q) {
        int L = q * 256 + tid;                 // 0..511
        int u = L >> 3, c = L & 7;
        int v = c ^ (u & 7);
        int r = 2 * u + (v & 1);               // source row 0..127
        int s = v >> 1;                        // source granule 0..3
        srcA[q] = A + (size_t)(m0 + r) * K + s * 4;
        srcW[q] = W + (size_t)(n0 + r) * K + s * 4;
        dstA[q] = q * 1024 + w * 256;          // float offset (wave-uniform)
        dstW[q] = 2048 + q * 1024 + w * 256;   // W region starts at 8 KB
    }

    // ---- fragment read byte-offsets; granule gk of row r is at
    // u*128 + (((r&1)^(u&1))<<4) + ((((u>>1)&3) ^ gk)<<5).
    // base holds everything except gk; read addr = base ^ (gk<<5).
    // offA/offW also carry the double-buffer bit (^=16384 per tile).
    int offA[8], offW[8];
#pragma unroll
    for (int i = 0; i < 8; ++i) {
        int r = ty + 16 * i;
        int u = r >> 1, y = u & 7;
        offA[i] = u * 128 + (((r & 1) ^ (y & 1)) << 4) + ((y >> 1) << 5);
        r = tx + 16 * i;
        u = r >> 1; y = u & 7;
        offW[i] = 8192 + u * 128 + (((r & 1) ^ (y & 1)) << 4) + ((y >> 1) << 5);
    }

    float acc[8][8];                 // in-KC-block FMA chain
#pragma unroll
    for (int i = 0; i < 8; ++i)
#pragma unroll
        for (int j = 0; j < 8; ++j) acc[i][j] = 0.0f;

    const char* lbase = (const char*)&lds[0][0];
    const size_t cb = (size_t)(m0 + ty) * N + (n0 + tx);

#define STAGE(NB)                                                           \
    {                                                                       \
        _Pragma("unroll")                                                   \
        for (int q = 0; q < 2; ++q) {                                       \
            __builtin_amdgcn_global_load_lds((gas_cp)srcA[q],               \
                (las_p)&lds[NB][dstA[q]], 16, 0, 0);                        \
            __builtin_amdgcn_global_load_lds((gas_cp)srcW[q],               \
                (las_p)&lds[NB][dstW[q]], 16, 0, 0);                        \
            srcA[q] += BK;                                                  \
            srcW[q] += BK;                                                  \
        }                                                                   \
    }

// One granule (4 consecutive k): wv[8] reads, then av chunks 0..3 / 4..7.
// Per acc element: q ascends within granule, granules ascend -> exact chain.
#define GK4(GKL)                                                            \
    {                                                                       \
        float4 wv[8];                                                       \
        _Pragma("unroll")                                                   \
        for (int j = 0; j < 8; ++j)                                         \
            wv[j] = *(const float4*)(lbase + (offW[j] ^ (GKL)));            \
        {                                                                   \
            float4 av[4];                                                   \
            _Pragma("unroll")                                               \
            for (int i = 0; i < 4; ++i)                                     \
                av[i] = *(const float4*)(lbase + (offA[i] ^ (GKL)));        \
            _Pragma("unroll")                                               \
            for (int q = 0; q < 4; ++q)                                     \
                _Pragma("unroll")                                           \
                for (int i = 0; i < 4; ++i)                                 \
                    _Pragma("unroll")                                       \
                    for (int j = 0; j < 8; ++j)                             \
                        acc[i][j] = __builtin_fmaf(((const float*)&av[i])[q], \
                                                   ((const float*)&wv[j])[q], \
                                                   acc[i][j]);              \
        }                                                                   \
        {                                                                   \
            float4 av[4];                                                   \
            _Pragma("unroll")                                               \
            for (int i = 0; i < 4; ++i)                                     \
                av[i] = *(const float4*)(lbase + (offA[4 + i] ^ (GKL)));    \
            _Pragma("unroll")                                               \
            for (int q = 0; q < 4; ++q)                                     \
                _Pragma("unroll")                                           \
                for (int i = 0; i < 4; ++i)                                 \
                    _Pragma("unroll")                                       \
                    for (int j = 0; j < 8; ++j)                             \
                        acc[4 + i][j] = __builtin_fmaf(((const float*)&av[i])[q], \
                                                       ((const float*)&wv[j])[q], \
                                                       acc[4 + i][j]);      \
        }                                                                   \
    }

    // prologue: stage tile 0 into buffer 0
    STAGE(0)

    int cur = 0;
    for (int kt = 0; kt < 128; ++kt) {       // K = 2048 fixed: 128 BK-tiles
        __syncthreads();                     // buf[cur] staged & visible
        if (kt < 127) {
            int nb = cur ^ 1;
            STAGE(nb)
        }

        GK4(0) GK4(32) GK4(64) GK4(96)

        // KC=512 boundary (tiles 31/63/95/127): fold chain into C in global
        // memory, same thread, ascending KC order -> exact BLIS join.
        // volatile: forbids register-forwarding C across boundaries.
        if (((kt + 1) & 31) == 0) {
            volatile float* Cv = (volatile float*)C;
            if (kt == 31) {
#pragma unroll
                for (int i = 0; i < 8; ++i) {
                    size_t rowb = cb + (size_t)(i * 16) * N;
#pragma unroll
                    for (int j = 0; j < 8; ++j) {
                        Cv[rowb + j * 16] = acc[i][j];   // tot = 0 + c1 exact
                        acc[i][j] = 0.0f;
                    }
                }
            } else {
#pragma unroll
                for (int i = 0; i < 8; ++i) {
                    size_t rowb = cb + (size_t)(i * 16) * N;
#pragma unroll
                    for (int j = 0; j < 8; ++j) {
                        float t = Cv[rowb + j * 16];
                        Cv[rowb + j * 16] = t + acc[i][j];  // tot + c_b
                        acc[i][j] = 0.0f;
                    }
                }
            }
        }

#pragma unroll
        for (int i = 0; i < 8; ++i) { offA[i] ^= 16384; offW[i] ^= 16384; }
        cur ^= 1;
    }

#undef GK4
#undef STAGE
}

// ---------- kernel 2b: fp32 GEMM 64x128 tile, 4x8/thread (output layer) ------
// Round-1 kernel verbatim (proven). N=512: grid (4,64) = 256 blocks = 1/CU.
__global__ __launch_bounds__(256)
void k_gemm_seq(const float* __restrict__ A, const float* __restrict__ W,
                float* __restrict__ C, int M, int N, int K) {
    constexpr int BM = 64, BN = 128, BK = 32;
    constexpr int NT = 8;                       // n per thread (BN/16)
    constexpr int BUFF = (BM + BN) * BK;        // 6144 floats = 24 KB
    __shared__ alignas(16) float lds[2][BUFF];  // 48 KB double-buffered

    const int tid = threadIdx.x;
    const int tx  = tid & 15;        // n direction
    const int ty  = tid >> 4;        // m direction
    const int m0  = blockIdx.y * BM;
    const int n0  = blockIdx.x * BN;
    const int w   = tid >> 6;        // wave id 0..3

    const float* srcA[2];
    int dstA[2];
#pragma unroll
    for (int q = 0; q < 2; ++q) {
        int L = q * 256 + tid;
        int r = L >> 3;
        int s = ((L & 7) - ((r + (r >> 4)) & 7)) & 7;
        srcA[q] = A + (size_t)(m0 + r) * K + s * 4;
        dstA[q] = q * 1024 + w * 256;
    }
    const float* srcW[4];
    int dstW[4];
#pragma unroll
    for (int q = 0; q < 4; ++q) {
        int L = q * 256 + tid;
        int r = L >> 3;
        int s = ((L & 7) - ((r + (r >> 4)) & 7)) & 7;
        srcW[q] = W + (size_t)(n0 + r) * K + s * 4;
        dstW[q] = BM * BK + q * 1024 + w * 256;
    }

    float acc[4][NT];
    float tot[4][NT];
#pragma unroll
    for (int i = 0; i < 4; ++i)
#pragma unroll
        for (int j = 0; j < NT; ++j) { acc[i][j] = 0.0f; tot[i][j] = 0.0f; }

    const int nkt = K / BK;

#pragma unroll
    for (int q = 0; q < 2; ++q) {
        __builtin_amdgcn_global_load_lds((gas_cp)srcA[q], (las_p)&lds[0][dstA[q]], 16, 0, 0);
        srcA[q] += BK;
    }
#pragma unroll
    for (int q = 0; q < 4; ++q) {
        __builtin_amdgcn_global_load_lds((gas_cp)srcW[q], (las_p)&lds[0][dstW[q]], 16, 0, 0);
        srcW[q] += BK;
    }

    int cur = 0;
    for (int kt = 0; kt < nkt; ++kt) {
        __syncthreads();

        if (kt + 1 < nkt) {
            int nb = cur ^ 1;
#pragma unroll
            for (int q = 0; q < 2; ++q) {
                __builtin_amdgcn_global_load_lds((gas_cp)srcA[q], (las_p)&lds[nb][dstA[q]], 16, 0, 0);
                srcA[q] += BK;
            }
#pragma unroll
            for (int q = 0; q < 4; ++q) {
                __builtin_amdgcn_global_load_lds((gas_cp)srcW[q], (las_p)&lds[nb][dstW[q]], 16, 0, 0);
                srcW[q] += BK;
            }
        }

        const float* At = &lds[cur][0];
        const float* Wt = &lds[cur][BM * BK];

#pragma unroll
        for (int gk = 0; gk < 8; ++gk) {
            float4 av[4], wv[NT];
#pragma unroll
            for (int i = 0; i < 4; ++i) {
                int r = ty + 16 * i;
                int rot = (r + (r >> 4)) & 7;
                av[i] = *(const float4*)&At[r * BK + (((gk + rot) & 7) << 2)];
            }
#pragma unroll
            for (int j = 0; j < NT; ++j) {
                int r = tx + 16 * j;
                int rot = (r + (r >> 4)) & 7;
                wv[j] = *(const float4*)&Wt[r * BK + (((gk + rot) & 7) << 2)];
            }
#pragma unroll
            for (int q = 0; q < 4; ++q)
#pragma unroll
                for (int i = 0; i < 4; ++i)
#pragma unroll
                    for (int j = 0; j < NT; ++j)
                        acc[i][j] = __builtin_fmaf(((const float*)&av[i])[q],
                                                   ((const float*)&wv[j])[q],
                                                   acc[i][j]);
        }

        if (((kt + 1) & 15) == 0) {
#pragma unroll
            for (int i = 0; i < 4; ++i)
#pragma unroll
                for (int j = 0; j < NT; ++j) {
                    tot[i][j] = tot[i][j] + acc[i][j];
                    acc[i][j] = 0.0f;
                }
        }
        cur ^= 1;
    }

#pragma unroll
    for (int i = 0; i < 4; ++i)
#pragma unroll
        for (int j = 0; j < NT; ++j)
            C[(size_t)(m0 + ty + 16 * i) * N + (n0 + tx + 16 * j)] = tot[i][j];
}

// ---------- kernel 3: LIF scan over t for hidden layers (fp32, numpy order) --
__global__ __launch_bounds__(256) void k_scan_h(const float* __restrict__ Acc,
                                                const float* __restrict__ v_init,
                                                const float* __restrict__ s_init,
                                                const float* __restrict__ bias,
                                                float* __restrict__ Sout) {
    int idx = blockIdx.x * 256 + threadIdx.x;  // b*H + h
    int h = idx & (H_ - 1);
    float v = v_init[idx];
    float s = s_init[idx];
    float bb = bias[h];
#pragma unroll
    for (int t = 0; t < T_; ++t) {
        float x = Acc[(size_t)t * (B_ * H_) + idx];
        float d = 0.5f * v;          // exact (power of two)
        d = d * (1.0f - s);          // exact (x{0,1})
        v = d + x;
        v = v + bb;
        s = (v > 0.5f) ? 1.0f : 0.0f;
        Sout[(size_t)t * (B_ * H_) + idx] = s;
    }
}

// ---------- kernel 4: LIF scan + spike count for output layer ----------
__global__ __launch_bounds__(256) void k_scan_o(const float* __restrict__ Acc,
                                                const float* __restrict__ v_init,
                                                const float* __restrict__ s_init,
                                                const float* __restrict__ bias,
                                                float* __restrict__ out) {
    int idx = blockIdx.x * 256 + threadIdx.x;  // b*OUT + o
    int o = idx & (OUT_ - 1);
    float v = v_init[idx];
    float s = s_init[idx];
    float bb = bias[o];
    float acc = 0.0f;
#pragma unroll
    for (int t = 0; t < T_; ++t) {
        float x = Acc[(size_t)t * (B_ * OUT_) + idx];
        float d = 0.5f * v;
        d = d * (1.0f - s);
        v = d + x;
        v = v + bb;
        s = (v > 0.5f) ? 1.0f : 0.0f;
        acc += s;                    // integer-valued, exact in fp32
    }
    out[idx] = acc;
}

// ---------- launch ----------

extern "C" void kernel_launch(void* const* d_in, const int* in_sizes, int n_in,
                              void* d_out, int out_size, void* d_ws, size_t ws_size,
                              hipStream_t stream) {
    const float* spike_data = (const float*)d_in[0];
    const float* h0_volt  = (const float*)d_in[1];
    const float* h0_spike = (const float*)d_in[2];
    const float* h1_volt  = (const float*)d_in[3];
    const float* h1_spike = (const float*)d_in[4];
    const float* o_volt   = (const float*)d_in[5];
    const float* o_spike  = (const float*)d_in[6];
    const float* W0 = (const float*)d_in[7];
    const float* b0 = (const float*)d_in[8];
    const float* W1 = (const float*)d_in[9];
    const float* b1 = (const float*)d_in[10];
    const float* Wo = (const float*)d_in[11];
    const float* bo = (const float*)d_in[12];
    float* out = (float*)d_out;

    // workspace layout (96 MB)
    char* ws = (char*)d_ws;
    const size_t MB = (size_t)1 << 20;
    float* Xt = (float*)(ws);             // 32 MB [T*B][IN]; reused as S1
    float* S0 = (float*)(ws + 32 * MB);   // 32 MB [T*B][H]
    float* Ab = (float*)(ws + 64 * MB);   // 32 MB [T*B][H] (or [T*B][OUT])
    float* S1 = Xt;                       // Xt dead after GEMM0

    const int M = T_ * B_;   // 4096

    k_transpose<<<(B_ * IN_) / 256, 256, 0, stream>>>(spike_data, Xt);

    // layer 0: A0 = Xt @ W0^T   [4096,2048] x [2048,2048]  (K=2048 fixed)
    k_gemm_128<<<dim3(H_ / 128, M / 128), 256, 0, stream>>>(Xt, W0, Ab, M, H_, IN_);
    k_scan_h<<<(B_ * H_) / 256, 256, 0, stream>>>(Ab, h0_volt, h0_spike, b0, S0);

    // layer 1: A1 = S0 @ W1^T
    k_gemm_128<<<dim3(H_ / 128, M / 128), 256, 0, stream>>>(S0, W1, Ab, M, H_, H_);
    k_scan_h<<<(B_ * H_) / 256, 256, 0, stream>>>(Ab, h1_volt, h1_spike, b1, S1);

    // output: Ao = S1 @ Wo^T   [4096,2048] x [2048,512]
    k_gemm_seq<<<dim3(OUT_ / 128, M / 64), 256, 0, stream>>>(S1, Wo, Ab, M, OUT_, H_);
    k_scan_o<<<(B_ * OUT_) / 256, 256, 0, stream>>>(Ab, o_volt, o_spike, bo, out);

    (void)in_sizes; (void)n_in; (void)out_size; (void)ws_size;
}